// Round 9
// baseline (2861.711 us; speedup 1.0000x reference)
//
#include <hip/hip_runtime.h>
#include <cstddef>

#define NN 256      // N
#define PP 256      // P
#define BB 128      // B
#define KK 4        // K
#define NSYS 512    // K*B
#define PW 32       // panel width
#define NPAN (NN/PW)
#define PSTR 36     // panel LDS row stride (16B-aligned rows: 36*4=144B)

__device__ __forceinline__ float sigmoidf_(float x){ return 1.0f/(1.0f+expf(-x)); }

// ---------------------------------------------------------------------------
// Kernel 1: build Cm (A) and rowsum(Cm) for systems [s0,s0+cs)
// ---------------------------------------------------------------------------
__global__ __launch_bounds__(256) void build_kernel(
    const float* __restrict__ C, const float* __restrict__ rm,
    const float* __restrict__ epsp, const int* __restrict__ bad,
    float* __restrict__ A, float* __restrict__ rowsum, int s0)
{
  const int si = blockIdx.x;
  const int ls = si >> 8;
  const int i  = si & 255;
  const int s  = s0 + ls;
  const int k  = s >> 7;
  const int b  = s & 127;
  const int j  = threadIdx.x;

  const float sk = sigmoidf_(rm[k]);
  const float ek = sigmoidf_(epsp[k]);
  const bool bad_i = bad[b*NN + i] != 0;
  const bool bad_j = bad[b*NN + j] != 0;

  float c  = C[((size_t)b*NN + i)*(NN+PP) + j];
  float x  = sk * c;
  float cf = (1.0f + x) * expf(-x);
  if (i == j) cf += ek;              // diag: C[i][i]==0 -> cf==1, add eps
  float keep = (bad_i == bad_j) ? 1.0f : 0.0f;
  float a = cf * keep;
  A[((size_t)ls*NN + i)*NN + j] = a;

  __shared__ float red[256];
  red[j] = a; __syncthreads();
  #pragma unroll
  for (int off = 128; off > 0; off >>= 1){
    if (j < off) red[j] += red[j + off];
    __syncthreads();
  }
  if (j == 0) rowsum[ls*NN + i] = red[0];
}

// ---------------------------------------------------------------------------
// Kernel 2: swap-free blocked LU, panel rows REGISTERIZED.
// Thread t owns physical row t; its 32 panel values live in u[32] (VGPRs,
// compile-time indices only). Per column, only the pivot row goes through
// LDS (store + broadcast read). Pivot order -> pivseq.
// ---------------------------------------------------------------------------
__global__ __launch_bounds__(512, 4) void lu_kernel(
    float* __restrict__ Aall, int* __restrict__ permAll)
{
  __shared__ __align__(16) float panel[NN][PSTR];  // 36.9 KiB (written post-factor)
  __shared__ __align__(16) float prow[PSTR];       // pivot-row broadcast buffer
  __shared__ float linv[PW][PW+1];
  __shared__ float uinv[PW][PW+1];
  __shared__ float urow[PW][NN-PW];                // 28 KiB U12 staging
  __shared__ float redv[2][8];
  __shared__ int   redi[2][8];
  __shared__ int   pivseq[NN];
  __shared__ int   actlist[NN];
  __shared__ unsigned char pickedsh[NN];
  __shared__ int   nact;

  const int ls = blockIdx.x;
  float* __restrict__ A = Aall + (size_t)ls*NN*NN;
  const int t = threadIdx.x;
  const int lane = t & 63, wid = t >> 6;
  bool picked = false;
  if (t < NN) pickedsh[t] = 0;

  for (int I = 0; I < NPAN; ++I){
    const int col0 = I*PW;
    const int W = NN - col0 - PW;
    if (t == 0) nact = 0;
    __syncthreads();                 // guard panel/urow reuse + nact reset

    // ---- load my panel row into registers ----
    float u[PW];
    if (t < NN){
      const float4* Ar = (const float4*)(A + (size_t)t*NN + col0);
      float4 q0=Ar[0],q1=Ar[1],q2=Ar[2],q3=Ar[3],q4=Ar[4],q5=Ar[5],q6=Ar[6],q7=Ar[7];
      u[0]=q0.x;u[1]=q0.y;u[2]=q0.z;u[3]=q0.w;   u[4]=q1.x;u[5]=q1.y;u[6]=q1.z;u[7]=q1.w;
      u[8]=q2.x;u[9]=q2.y;u[10]=q2.z;u[11]=q2.w; u[12]=q3.x;u[13]=q3.y;u[14]=q3.z;u[15]=q3.w;
      u[16]=q4.x;u[17]=q4.y;u[18]=q4.z;u[19]=q4.w;u[20]=q5.x;u[21]=q5.y;u[22]=q5.z;u[23]=q5.w;
      u[24]=q6.x;u[25]=q6.y;u[26]=q6.z;u[27]=q6.w;u[28]=q7.x;u[29]=q7.y;u[30]=q7.z;u[31]=q7.w;
    }

    // ---- initial argmax (col 0) over active rows ----
    {
      float v = -1.0f; int vi = t;
      if (t < NN && !picked) v = fabsf(u[0]);
      #pragma unroll
      for (int off = 32; off > 0; off >>= 1){
        float ov = __shfl_down(v, off); int oi = __shfl_down(vi, off);
        if (ov > v){ v = ov; vi = oi; }
      }
      if (lane == 0){ redv[0][wid] = v; redi[0][wid] = vi; }
    }
    __syncthreads();

    // ---- panel factor: pivot row via LDS broadcast, all else in regs ----
    for (int c = 0; c < PW; ++c){
      const int par = c & 1;
      float bv = redv[par][0]; int p = redi[par][0];
      #pragma unroll
      for (int w = 1; w < 8; ++w)
        if (redv[par][w] > bv){ bv = redv[par][w]; p = redi[par][w]; }
      if (t == p){
        picked = true; pickedsh[t] = 1; pivseq[col0+c] = t;
        float4* Pw = (float4*)prow;
        Pw[0]=make_float4(u[0],u[1],u[2],u[3]);     Pw[1]=make_float4(u[4],u[5],u[6],u[7]);
        Pw[2]=make_float4(u[8],u[9],u[10],u[11]);   Pw[3]=make_float4(u[12],u[13],u[14],u[15]);
        Pw[4]=make_float4(u[16],u[17],u[18],u[19]); Pw[5]=make_float4(u[20],u[21],u[22],u[23]);
        Pw[6]=make_float4(u[24],u[25],u[26],u[27]); Pw[7]=make_float4(u[28],u[29],u[30],u[31]);
        float pd = u[0];
        #pragma unroll
        for (int j = 0; j < PW; ++j) if (j == c) pd = u[j];
        prow[32] = pd;
      }
      __syncthreads();

      float pr[PW];
      {
        const float4* Pr = (const float4*)prow;
        float4 p0=Pr[0],p1=Pr[1],p2=Pr[2],p3=Pr[3],p4=Pr[4],p5=Pr[5],p6=Pr[6],p7=Pr[7];
        pr[0]=p0.x;pr[1]=p0.y;pr[2]=p0.z;pr[3]=p0.w;   pr[4]=p1.x;pr[5]=p1.y;pr[6]=p1.z;pr[7]=p1.w;
        pr[8]=p2.x;pr[9]=p2.y;pr[10]=p2.z;pr[11]=p2.w; pr[12]=p3.x;pr[13]=p3.y;pr[14]=p3.z;pr[15]=p3.w;
        pr[16]=p4.x;pr[17]=p4.y;pr[18]=p4.z;pr[19]=p4.w;pr[20]=p5.x;pr[21]=p5.y;pr[22]=p5.z;pr[23]=p5.w;
        pr[24]=p6.x;pr[25]=p6.y;pr[26]=p6.z;pr[27]=p6.w;pr[28]=p7.x;pr[29]=p7.y;pr[30]=p7.z;pr[31]=p7.w;
      }
      const float rdia = 1.0f / prow[32];

      float nv = -1.0f; int ni = t;
      if (t < NN && !picked){
        float uc = u[0];
        #pragma unroll
        for (int j = 0; j < PW; ++j) if (j == c) uc = u[j];
        const float m = uc * rdia;
        #pragma unroll
        for (int j = 0; j < PW; ++j){
          if (j > c)       u[j] = u[j] - m * pr[j];
          else if (j == c) u[j] = m;
        }
        #pragma unroll
        for (int j = 0; j < PW; ++j) if (j == c+1) nv = fabsf(u[j]);
      }
      #pragma unroll
      for (int off = 32; off > 0; off >>= 1){
        float ov = __shfl_down(nv, off); int oi = __shfl_down(ni, off);
        if (ov > nv){ nv = ov; ni = oi; }
      }
      if (lane == 0){ redv[par^1][wid] = nv; redi[par^1][wid] = ni; }
      __syncthreads();
    }

    // ---- publish factored rows to LDS panel ----
    if (t < NN){
      float4* Pp = (float4*)&panel[t][0];
      Pp[0]=make_float4(u[0],u[1],u[2],u[3]);     Pp[1]=make_float4(u[4],u[5],u[6],u[7]);
      Pp[2]=make_float4(u[8],u[9],u[10],u[11]);   Pp[3]=make_float4(u[12],u[13],u[14],u[15]);
      Pp[4]=make_float4(u[16],u[17],u[18],u[19]); Pp[5]=make_float4(u[20],u[21],u[22],u[23]);
      Pp[6]=make_float4(u[24],u[25],u[26],u[27]); Pp[7]=make_float4(u[28],u[29],u[30],u[31]);
    }
    __syncthreads();

    // ---- concurrent: U12 (waves 4-7) | Linv (t<32) | Uinv (64..95) | actlist ----
    if (t >= 256){
      const int jj = t - 256;
      if (jj < W){
        const int j = col0 + PW + jj;
        float uu[PW];
        #pragma unroll
        for (int c = 0; c < PW; ++c) uu[c] = A[(size_t)pivseq[col0+c]*NN + j];
        #pragma unroll
        for (int c = 0; c < PW; ++c){
          const int pc = pivseq[col0+c];
          float sv = uu[c];
          #pragma unroll
          for (int k2 = 0; k2 < PW; ++k2)
            if (k2 < c) sv -= panel[pc][k2] * uu[k2];
          uu[c] = sv;
          urow[c][jj] = sv;
          A[(size_t)pc*NN + j] = sv;
        }
      }
    } else if (t < PW){
      const int cth = t;
      for (int r = cth; r < PW; ++r){
        float sv = (r == cth) ? 1.0f : 0.0f;
        const int pr2 = pivseq[col0+r];
        for (int k2 = cth; k2 < r; ++k2) sv -= panel[pr2][k2] * linv[k2][cth];
        linv[r][cth] = sv;
      }
    } else if (t >= 64 && t < 64+PW){
      const int cth = t - 64;
      for (int r = cth; r >= 0; --r){
        float sv = (r == cth) ? 1.0f : 0.0f;
        const int pr2 = pivseq[col0+r];
        for (int k2 = r+1; k2 <= cth; ++k2) sv -= panel[pr2][k2] * uinv[k2][cth];
        uinv[r][cth] = sv / panel[pr2][r];
      }
    } else if (t >= 128 && t < 192){
      #pragma unroll
      for (int q = 0; q < 4; ++q){
        int r = (t-128)*4 + q;
        if (!pickedsh[r]){ int pos = atomicAdd(&nact, 1); actlist[pos] = r; }
      }
    }
    __syncthreads();

    // ---- writeback: packed diag inverses + L multipliers ----
    for (int e = t; e < PW*PW; e += 512){
      int r = e >> 5, c2 = e & 31;
      A[(size_t)pivseq[col0+r]*NN + col0 + c2] = (r > c2) ? linv[r][c2] : uinv[r][c2];
    }
    for (int e = t; e < NN*PW; e += 512){
      int r = e >> 5, c2 = e & 31;
      if (!pickedsh[r]) A[(size_t)r*NN + col0 + c2] = panel[r][c2];
    }

    // ---- trailing update: active rows -= L21 * U12 (float4, 1 col pass) ----
    if (W > 0){
      for (int i0 = wid*2; i0 < W; i0 += 16){
        const int r0 = actlist[i0];
        const int r1 = actlist[i0+1];          // W even: pair valid
        float4* R0 = (float4*)(A + (size_t)r0*NN + col0 + PW);
        float4* R1 = (float4*)(A + (size_t)r1*NN + col0 + PW);
        if (lane*4 < W){
          float4 a0 = R0[lane];
          float4 a1 = R1[lane];
          #pragma unroll
          for (int c = 0; c < PW; ++c){
            float4 u4 = *(const float4*)&urow[c][lane*4];
            float p0 = panel[r0][c], p1 = panel[r1][c];
            a0.x -= p0*u4.x; a0.y -= p0*u4.y; a0.z -= p0*u4.z; a0.w -= p0*u4.w;
            a1.x -= p1*u4.x; a1.y -= p1*u4.y; a1.z -= p1*u4.z; a1.w -= p1*u4.w;
          }
          R0[lane] = a0;
          R1[lane] = a1;
        }
      }
    }
  }
  __syncthreads();
  if (t < NN) permAll[ls*NN + t] = pivseq[t];
}

// ---------------------------------------------------------------------------
// Kernel 3: blocked triangular solves + epilogue for ONE 64-col RHS chunk.
// XCD-swizzled grid; rank-32 updates with ALL 16 row-pair loads hoisted into
// named registers (16 loads in flight per iteration).
// ---------------------------------------------------------------------------
__global__ __launch_bounds__(512, 4) void solve_epi_kernel(
    const float* __restrict__ Aall, const int* __restrict__ permAll,
    const float* __restrict__ rowsum,
    const float* __restrict__ C, const float* __restrict__ val,
    const int* __restrict__ bad, const float* __restrict__ rm,
    float* __restrict__ out, int s0)
{
  __shared__ float tile[NN][64];      // 64 KiB
  __shared__ float dblk[PW][PW+1];
  __shared__ float ep[4][8][64];
  __shared__ int   perm[NN];

  int ls, c0;
  {
    const int g = blockIdx.x;
    if ((gridDim.x & 31) == 0){       // cs % 8 == 0: XCD co-location swizzle
      const int xcd = g & 7, idx = g >> 3;
      ls = xcd + 8*(idx >> 2);
      c0 = (idx & 3) * 64;
    } else {
      ls = g >> 2;
      c0 = (g & 3) * 64;
    }
  }
  const int s  = s0 + ls;
  const int k  = s >> 7, b = s & 127;
  const float* __restrict__ A = Aall + (size_t)ls*NN*NN;
  const float* __restrict__ rs = rowsum + ls*NN;
  const int t = threadIdx.x;
  const int lane = t & 63, wid = t >> 6;
  const float sk = sigmoidf_(rm[k]);

  if (t < NN) perm[t] = permAll[ls*NN + t];
  __syncthreads();

  // ---- build permuted RHS chunk on the fly ----
  for (int e = t; e < NN*64; e += 512){
    int i = e >> 6, c = e & 63;
    int pi = perm[i];
    float cb = C[((size_t)b*NN + pi)*(NN+PP) + NN + c0 + c];
    float xb = sk * cb;
    float bf = (1.0f + xb) * expf(-xb);
    if (bad[b*NN + pi]) bf = 0.0f;
    tile[i][c] = bf;
  }
  __syncthreads();

  // ---- forward: y = Linv-chain applied to Pb ----
  for (int J = 0; J < NPAN; ++J){
    const int j0 = J*PW;
    for (int e = t; e < PW*PW; e += 512){
      int r = e >> 5, c = e & 31;
      dblk[r][c] = A[(size_t)perm[j0+r]*NN + j0 + c];
    }
    __syncthreads();
    const int r0 = wid*4;
    float y0 = tile[j0+r0+0][lane];
    float y1 = tile[j0+r0+1][lane];
    float y2 = tile[j0+r0+2][lane];
    float y3 = tile[j0+r0+3][lane];
    for (int kk = 0; kk < r0; ++kk){
      float xk = tile[j0+kk][lane];
      y0 += dblk[r0+0][kk]*xk;
      y1 += dblk[r0+1][kk]*xk;
      y2 += dblk[r0+2][kk]*xk;
      y3 += dblk[r0+3][kk]*xk;
    }
    {
      float x0 = tile[j0+r0][lane], x1 = tile[j0+r0+1][lane], x2 = tile[j0+r0+2][lane];
      y1 += dblk[r0+1][r0]*x0;
      y2 += dblk[r0+2][r0]*x0 + dblk[r0+2][r0+1]*x1;
      y3 += dblk[r0+3][r0]*x0 + dblk[r0+3][r0+1]*x1 + dblk[r0+3][r0+2]*x2;
    }
    __syncthreads();
    tile[j0+r0+0][lane]=y0; tile[j0+r0+1][lane]=y1;
    tile[j0+r0+2][lane]=y2; tile[j0+r0+3][lane]=y3;
    __syncthreads();
    if (j0 + PW < NN){
      float x[PW];
      #pragma unroll
      for (int kk = 0; kk < PW; ++kk) x[kk] = tile[j0+kk][lane];
      const int nbelow = NN - j0 - PW;
      for (int i0 = wid*2; i0 < nbelow; i0 += 16){
        const int ia = j0 + PW + i0, ib = ia + 1;
        const float4* __restrict__ Ar0 = (const float4*)(A + (size_t)perm[ia]*NN + j0);
        const float4* __restrict__ Ar1 = (const float4*)(A + (size_t)perm[ib]*NN + j0);
        // hoist ALL 16 loads (in flight together), then FMA
        float4 A0=Ar0[0],A1=Ar0[1],A2=Ar0[2],A3=Ar0[3],A4=Ar0[4],A5=Ar0[5],A6=Ar0[6],A7=Ar0[7];
        float4 B0=Ar1[0],B1=Ar1[1],B2=Ar1[2],B3=Ar1[3],B4=Ar1[4],B5=Ar1[5],B6=Ar1[6],B7=Ar1[7];
        float acc0 = tile[ia][lane];
        float acc1 = tile[ib][lane];
        acc0 -= A0.x*x[0]  + A0.y*x[1]  + A0.z*x[2]  + A0.w*x[3];
        acc0 -= A1.x*x[4]  + A1.y*x[5]  + A1.z*x[6]  + A1.w*x[7];
        acc0 -= A2.x*x[8]  + A2.y*x[9]  + A2.z*x[10] + A2.w*x[11];
        acc0 -= A3.x*x[12] + A3.y*x[13] + A3.z*x[14] + A3.w*x[15];
        acc0 -= A4.x*x[16] + A4.y*x[17] + A4.z*x[18] + A4.w*x[19];
        acc0 -= A5.x*x[20] + A5.y*x[21] + A5.z*x[22] + A5.w*x[23];
        acc0 -= A6.x*x[24] + A6.y*x[25] + A6.z*x[26] + A6.w*x[27];
        acc0 -= A7.x*x[28] + A7.y*x[29] + A7.z*x[30] + A7.w*x[31];
        acc1 -= B0.x*x[0]  + B0.y*x[1]  + B0.z*x[2]  + B0.w*x[3];
        acc1 -= B1.x*x[4]  + B1.y*x[5]  + B1.z*x[6]  + B1.w*x[7];
        acc1 -= B2.x*x[8]  + B2.y*x[9]  + B2.z*x[10] + B2.w*x[11];
        acc1 -= B3.x*x[12] + B3.y*x[13] + B3.z*x[14] + B3.w*x[15];
        acc1 -= B4.x*x[16] + B4.y*x[17] + B4.z*x[18] + B4.w*x[19];
        acc1 -= B5.x*x[20] + B5.y*x[21] + B5.z*x[22] + B5.w*x[23];
        acc1 -= B6.x*x[24] + B6.y*x[25] + B6.z*x[26] + B6.w*x[27];
        acc1 -= B7.x*x[28] + B7.y*x[29] + B7.z*x[30] + B7.w*x[31];
        tile[ia][lane] = acc0;
        tile[ib][lane] = acc1;
      }
    }
    __syncthreads();
  }

  // ---- backward: d = Uinv-chain applied to y ----
  for (int J = NPAN-1; J >= 0; --J){
    const int j0 = J*PW;
    for (int e = t; e < PW*PW; e += 512){
      int r = e >> 5, c = e & 31;
      dblk[r][c] = A[(size_t)perm[j0+r]*NN + j0 + c];
    }
    __syncthreads();
    const int r0 = wid*4;
    float y0=0.f, y1=0.f, y2=0.f, y3=0.f;
    for (int kk = r0+4; kk < PW; ++kk){
      float xk = tile[j0+kk][lane];
      y0 += dblk[r0+0][kk]*xk;
      y1 += dblk[r0+1][kk]*xk;
      y2 += dblk[r0+2][kk]*xk;
      y3 += dblk[r0+3][kk]*xk;
    }
    {
      float x0 = tile[j0+r0][lane], x1 = tile[j0+r0+1][lane];
      float x2 = tile[j0+r0+2][lane], x3 = tile[j0+r0+3][lane];
      y0 += dblk[r0][r0]*x0 + dblk[r0][r0+1]*x1 + dblk[r0][r0+2]*x2 + dblk[r0][r0+3]*x3;
      y1 += dblk[r0+1][r0+1]*x1 + dblk[r0+1][r0+2]*x2 + dblk[r0+1][r0+3]*x3;
      y2 += dblk[r0+2][r0+2]*x2 + dblk[r0+2][r0+3]*x3;
      y3 += dblk[r0+3][r0+3]*x3;
    }
    __syncthreads();
    tile[j0+r0+0][lane]=y0; tile[j0+r0+1][lane]=y1;
    tile[j0+r0+2][lane]=y2; tile[j0+r0+3][lane]=y3;
    __syncthreads();
    if (j0 > 0){
      float x[PW];
      #pragma unroll
      for (int kk = 0; kk < PW; ++kk) x[kk] = tile[j0+kk][lane];
      for (int i0 = wid*2; i0 < j0; i0 += 16){
        const int ia = i0, ib = i0 + 1;
        const float4* __restrict__ Ar0 = (const float4*)(A + (size_t)perm[ia]*NN + j0);
        const float4* __restrict__ Ar1 = (const float4*)(A + (size_t)perm[ib]*NN + j0);
        float4 A0=Ar0[0],A1=Ar0[1],A2=Ar0[2],A3=Ar0[3],A4=Ar0[4],A5=Ar0[5],A6=Ar0[6],A7=Ar0[7];
        float4 B0=Ar1[0],B1=Ar1[1],B2=Ar1[2],B3=Ar1[3],B4=Ar1[4],B5=Ar1[5],B6=Ar1[6],B7=Ar1[7];
        float acc0 = tile[ia][lane];
        float acc1 = tile[ib][lane];
        acc0 -= A0.x*x[0]  + A0.y*x[1]  + A0.z*x[2]  + A0.w*x[3];
        acc0 -= A1.x*x[4]  + A1.y*x[5]  + A1.z*x[6]  + A1.w*x[7];
        acc0 -= A2.x*x[8]  + A2.y*x[9]  + A2.z*x[10] + A2.w*x[11];
        acc0 -= A3.x*x[12] + A3.y*x[13] + A3.z*x[14] + A3.w*x[15];
        acc0 -= A4.x*x[16] + A4.y*x[17] + A4.z*x[18] + A4.w*x[19];
        acc0 -= A5.x*x[20] + A5.y*x[21] + A5.z*x[22] + A5.w*x[23];
        acc0 -= A6.x*x[24] + A6.y*x[25] + A6.z*x[26] + A6.w*x[27];
        acc0 -= A7.x*x[28] + A7.y*x[29] + A7.z*x[30] + A7.w*x[31];
        acc1 -= B0.x*x[0]  + B0.y*x[1]  + B0.z*x[2]  + B0.w*x[3];
        acc1 -= B1.x*x[4]  + B1.y*x[5]  + B1.z*x[6]  + B1.w*x[7];
        acc1 -= B2.x*x[8]  + B2.y*x[9]  + B2.z*x[10] + B2.w*x[11];
        acc1 -= B3.x*x[12] + B3.y*x[13] + B3.z*x[14] + B3.w*x[15];
        acc1 -= B4.x*x[16] + B4.y*x[17] + B4.z*x[18] + B4.w*x[19];
        acc1 -= B5.x*x[20] + B5.y*x[21] + B5.z*x[22] + B5.w*x[23];
        acc1 -= B6.x*x[24] + B6.y*x[25] + B6.z*x[26] + B6.w*x[27];
        acc1 -= B7.x*x[28] + B7.y*x[29] + B7.z*x[30] + B7.w*x[31];
        tile[ia][lane] = acc0;
        tile[ib][lane] = acc1;
      }
    }
    __syncthreads();
  }

  // ---- epilogue: 8-wave partial column reductions + combine ----
  {
    const int p = c0 + lane;
    float sdv=0.f, sabs=0.f, s1v=0.f, s1=0.f;
    for (int j = wid*32; j < wid*32 + 32; ++j){
      float d = tile[j][lane];
      float v = val[(b*NN + j)*KK + k];
      if (v != v) v = 0.0f;
      float cb = C[((size_t)b*NN + j)*(NN+PP) + NN + p];
      float xb = sk*cb;
      float bo = (1.0f+xb)*expf(-xb);
      if (bad[b*NN + j]) bo = 0.0f;
      float d1 = bo / rs[j];
      sdv += d*v; sabs += fabsf(d); s1v += d1*v; s1 += d1;
    }
    ep[0][wid][lane]=sdv; ep[1][wid][lane]=sabs; ep[2][wid][lane]=s1v; ep[3][wid][lane]=s1;
  }
  __syncthreads();
  if (t < 64){
    float sdv=0.f, sabs=0.f, s1v=0.f, s1=0.f;
    #pragma unroll
    for (int w = 0; w < 8; ++w){
      sdv += ep[0][w][lane]; sabs += ep[1][w][lane];
      s1v += ep[2][w][lane]; s1  += ep[3][w][lane];
    }
    float wg    = fminf(fmaxf((sabs - 1.0f)*2.0f, 0.0f), 1.0f);
    float denom = fmaxf(s1, 1.0f);
    out[((size_t)b*PP + c0 + lane)*KK + k] = (1.0f - wg)*sdv + (wg/denom)*s1v;
  }
}

// ---------------------------------------------------------------------------
extern "C" void kernel_launch(void* const* d_in, const int* in_sizes, int n_in,
                              void* d_out, int out_size, void* d_ws, size_t ws_size,
                              hipStream_t stream)
{
  (void)in_sizes; (void)n_in; (void)out_size;
  const float* C    = (const float*)d_in[0];
  const float* val  = (const float*)d_in[1];
  const float* rm   = (const float*)d_in[2];
  const float* epsp = (const float*)d_in[3];
  const int*   bad  = (const int*)d_in[4];
  float* out = (float*)d_out;

  // per-system workspace: A (NN*NN f32) + rowsum (NN f32) + perm (NN i32)
  const size_t per_sys = (size_t)NN*NN*4 + (size_t)NN*4 + (size_t)NN*4;
  int chunk = (int)(ws_size / per_sys);
  if (chunk < 1)    chunk = 1;
  if (chunk > NSYS) chunk = NSYS;

  float* ws     = (float*)d_ws;
  float* A      = ws;
  float* rowsum = A + (size_t)chunk*NN*NN;
  int*   perm   = (int*)(rowsum + (size_t)chunk*NN);

  for (int s0 = 0; s0 < NSYS; s0 += chunk){
    int cs = (NSYS - s0 < chunk) ? (NSYS - s0) : chunk;
    build_kernel<<<cs*NN, 256, 0, stream>>>(C, rm, epsp, bad, A, rowsum, s0);
    lu_kernel<<<cs, 512, 0, stream>>>(A, perm);
    solve_epi_kernel<<<cs*4, 512, 0, stream>>>(A, perm, rowsum, C, val, bad, rm, out, s0);
  }
}

// Round 10
// 1750.190 us; speedup vs baseline: 1.6351x; 1.6351x over previous
//
#include <hip/hip_runtime.h>
#include <cstddef>

#define NN 256      // N
#define PP 256      // P
#define BB 128      // B
#define KK 4        // K
#define NSYS 512    // K*B
#define PW 32       // panel width
#define NPAN (NN/PW)

__device__ __forceinline__ float sigmoidf_(float x){ return 1.0f/(1.0f+expf(-x)); }

// ---------------------------------------------------------------------------
// Kernel 1: build Cm (A) and rowsum(Cm) for systems [s0,s0+cs)
// ---------------------------------------------------------------------------
__global__ __launch_bounds__(256) void build_kernel(
    const float* __restrict__ C, const float* __restrict__ rm,
    const float* __restrict__ epsp, const int* __restrict__ bad,
    float* __restrict__ A, float* __restrict__ rowsum, int s0)
{
  const int si = blockIdx.x;
  const int ls = si >> 8;
  const int i  = si & 255;
  const int s  = s0 + ls;
  const int k  = s >> 7;
  const int b  = s & 127;
  const int j  = threadIdx.x;

  const float sk = sigmoidf_(rm[k]);
  const float ek = sigmoidf_(epsp[k]);
  const bool bad_i = bad[b*NN + i] != 0;
  const bool bad_j = bad[b*NN + j] != 0;

  float c  = C[((size_t)b*NN + i)*(NN+PP) + j];
  float x  = sk * c;
  float cf = (1.0f + x) * expf(-x);
  if (i == j) cf += ek;              // diag: C[i][i]==0 -> cf==1, add eps
  float keep = (bad_i == bad_j) ? 1.0f : 0.0f;
  float a = cf * keep;
  A[((size_t)ls*NN + i)*NN + j] = a;

  __shared__ float red[256];
  red[j] = a; __syncthreads();
  #pragma unroll
  for (int off = 128; off > 0; off >>= 1){
    if (j < off) red[j] += red[j + off];
    __syncthreads();
  }
  if (j == 0) rowsum[ls*NN + i] = red[0];
}

// ---------------------------------------------------------------------------
// Kernel 2: swap-free blocked LU with partial pivoting ("pick-order").
// Rows never move: thread t owns physical row t; pivot order -> pivseq.
// (round-8 version — measured good: no spill, ~650 us)
// ---------------------------------------------------------------------------
__global__ __launch_bounds__(512, 4) void lu_kernel(
    float* __restrict__ Aall, int* __restrict__ permAll)
{
  __shared__ float panel[NN][PW+1];
  __shared__ float linv[PW][PW+1];
  __shared__ float uinv[PW][PW+1];
  __shared__ float urow[PW][NN-PW];
  __shared__ float redv[2][8];
  __shared__ int   redi[2][8];
  __shared__ int   pivseq[NN];
  __shared__ int   actlist[NN];
  __shared__ unsigned char pickedsh[NN];
  __shared__ int   nact;

  const int ls = blockIdx.x;
  float* __restrict__ A = Aall + (size_t)ls*NN*NN;
  const int t = threadIdx.x;
  const int lane = t & 63, wid = t >> 6;
  bool picked = false;
  if (t < NN) pickedsh[t] = 0;

  for (int I = 0; I < NPAN; ++I){
    const int col0 = I*PW;
    const int W = NN - col0 - PW;
    if (t == 0) nact = 0;
    __syncthreads();

    for (int e = t; e < NN*PW; e += 512){
      int r = e >> 5, c = e & 31;
      panel[r][c] = A[(size_t)r*NN + col0 + c];
    }
    __syncthreads();

    {
      float v = -1.0f; int vi = 0;
      if (t < NN && !picked){ v = fabsf(panel[t][0]); vi = t; }
      #pragma unroll
      for (int off = 32; off > 0; off >>= 1){
        float ov = __shfl_down(v, off); int oi = __shfl_down(vi, off);
        if (ov > v){ v = ov; vi = oi; }
      }
      if (lane == 0){ redv[0][wid] = v; redi[0][wid] = vi; }
    }
    __syncthreads();

    for (int c = 0; c < PW; ++c){
      const int par = c & 1;
      float bv = redv[par][0]; int p = redi[par][0];
      #pragma unroll
      for (int w = 1; w < 8; ++w)
        if (redv[par][w] > bv){ bv = redv[par][w]; p = redi[par][w]; }
      if (t == p){ picked = true; pickedsh[t] = 1; pivseq[col0+c] = t; }

      float nv = -1.0f; int ni = t;
      if (t < NN && !picked){
        const float rdia = 1.0f / panel[p][c];
        float m = panel[t][c] * rdia;
        panel[t][c] = m;
        float nxt = -1.0f;
        #pragma unroll
        for (int j = 0; j < PW; ++j){
          if (j > c){
            float u = panel[t][j] - m * panel[p][j];
            panel[t][j] = u;
            if (j == c+1) nxt = fabsf(u);
          }
        }
        nv = nxt;
      }
      #pragma unroll
      for (int off = 32; off > 0; off >>= 1){
        float ov = __shfl_down(nv, off); int oi = __shfl_down(ni, off);
        if (ov > nv){ nv = ov; ni = oi; }
      }
      if (lane == 0){ redv[par^1][wid] = nv; redi[par^1][wid] = ni; }
      __syncthreads();
    }

    if (t >= 256){
      const int jj = t - 256;
      if (jj < W){
        const int j = col0 + PW + jj;
        float u[PW];
        #pragma unroll
        for (int c = 0; c < PW; ++c) u[c] = A[(size_t)pivseq[col0+c]*NN + j];
        #pragma unroll
        for (int c = 0; c < PW; ++c){
          const int pc = pivseq[col0+c];
          float sv = u[c];
          #pragma unroll
          for (int k2 = 0; k2 < PW; ++k2)
            if (k2 < c) sv -= panel[pc][k2] * u[k2];
          u[c] = sv;
          urow[c][jj] = sv;
          A[(size_t)pc*NN + j] = sv;
        }
      }
    } else if (t < PW){
      const int cth = t;
      for (int r = cth; r < PW; ++r){
        float sv = (r == cth) ? 1.0f : 0.0f;
        const int pr = pivseq[col0+r];
        for (int k2 = cth; k2 < r; ++k2) sv -= panel[pr][k2] * linv[k2][cth];
        linv[r][cth] = sv;
      }
    } else if (t >= 64 && t < 64+PW){
      const int cth = t - 64;
      for (int r = cth; r >= 0; --r){
        float sv = (r == cth) ? 1.0f : 0.0f;
        const int pr = pivseq[col0+r];
        for (int k2 = r+1; k2 <= cth; ++k2) sv -= panel[pr][k2] * uinv[k2][cth];
        uinv[r][cth] = sv / panel[pr][r];
      }
    } else if (t >= 128 && t < 192){
      #pragma unroll
      for (int q = 0; q < 4; ++q){
        int r = (t-128)*4 + q;
        if (!pickedsh[r]){ int pos = atomicAdd(&nact, 1); actlist[pos] = r; }
      }
    }
    __syncthreads();

    for (int e = t; e < PW*PW; e += 512){
      int r = e >> 5, c2 = e & 31;
      A[(size_t)pivseq[col0+r]*NN + col0 + c2] = (r > c2) ? linv[r][c2] : uinv[r][c2];
    }
    for (int e = t; e < NN*PW; e += 512){
      int r = e >> 5, c2 = e & 31;
      if (!pickedsh[r]) A[(size_t)r*NN + col0 + c2] = panel[r][c2];
    }

    // ---- trailing update: active rows -= L21 * U12 (float4, 1 pass over cols) ----
    if (W > 0){
      for (int i0 = wid*2; i0 < W; i0 += 16){
        const int r0 = actlist[i0];
        const int r1 = actlist[i0+1];          // W is even: pair always valid
        float4* R0 = (float4*)(A + (size_t)r0*NN + col0 + PW);
        float4* R1 = (float4*)(A + (size_t)r1*NN + col0 + PW);
        if (lane*4 < W){
          float4 a0 = R0[lane];
          float4 a1 = R1[lane];
          #pragma unroll
          for (int c = 0; c < PW; ++c){
            float4 u4 = *(const float4*)&urow[c][lane*4];
            float p0 = panel[r0][c], p1 = panel[r1][c];
            a0.x -= p0*u4.x; a0.y -= p0*u4.y; a0.z -= p0*u4.z; a0.w -= p0*u4.w;
            a1.x -= p1*u4.x; a1.y -= p1*u4.y; a1.z -= p1*u4.z; a1.w -= p1*u4.w;
          }
          R0[lane] = a0;
          R1[lane] = a1;
        }
      }
    }
  }
  __syncthreads();
  if (t < NN) permAll[ls*NN + t] = pivseq[t];
}

// ---------------------------------------------------------------------------
// Kernel 3: blocked triangular solves + epilogue for ONE 64-col RHS chunk.
// XCD-swizzled grid; rank-32 updates with ALL 16 row-pair loads hoisted into
// named registers (16 loads in flight per iteration).
// ---------------------------------------------------------------------------
__global__ __launch_bounds__(512, 4) void solve_epi_kernel(
    const float* __restrict__ Aall, const int* __restrict__ permAll,
    const float* __restrict__ rowsum,
    const float* __restrict__ C, const float* __restrict__ val,
    const int* __restrict__ bad, const float* __restrict__ rm,
    float* __restrict__ out, int s0)
{
  __shared__ float tile[NN][64];      // 64 KiB
  __shared__ float dblk[PW][PW+1];
  __shared__ float ep[4][8][64];
  __shared__ int   perm[NN];

  int ls, c0;
  {
    const int g = blockIdx.x;
    if ((gridDim.x & 31) == 0){       // cs % 8 == 0: XCD co-location swizzle
      const int xcd = g & 7, idx = g >> 3;
      ls = xcd + 8*(idx >> 2);
      c0 = (idx & 3) * 64;
    } else {
      ls = g >> 2;
      c0 = (g & 3) * 64;
    }
  }
  const int s  = s0 + ls;
  const int k  = s >> 7, b = s & 127;
  const float* __restrict__ A = Aall + (size_t)ls*NN*NN;
  const float* __restrict__ rs = rowsum + ls*NN;
  const int t = threadIdx.x;
  const int lane = t & 63, wid = t >> 6;
  const float sk = sigmoidf_(rm[k]);

  if (t < NN) perm[t] = permAll[ls*NN + t];
  __syncthreads();

  // ---- build permuted RHS chunk on the fly ----
  for (int e = t; e < NN*64; e += 512){
    int i = e >> 6, c = e & 63;
    int pi = perm[i];
    float cb = C[((size_t)b*NN + pi)*(NN+PP) + NN + c0 + c];
    float xb = sk * cb;
    float bf = (1.0f + xb) * expf(-xb);
    if (bad[b*NN + pi]) bf = 0.0f;
    tile[i][c] = bf;
  }
  __syncthreads();

  // ---- forward: y = Linv-chain applied to Pb ----
  for (int J = 0; J < NPAN; ++J){
    const int j0 = J*PW;
    for (int e = t; e < PW*PW; e += 512){
      int r = e >> 5, c = e & 31;
      dblk[r][c] = A[(size_t)perm[j0+r]*NN + j0 + c];
    }
    __syncthreads();
    const int r0 = wid*4;
    float y0 = tile[j0+r0+0][lane];
    float y1 = tile[j0+r0+1][lane];
    float y2 = tile[j0+r0+2][lane];
    float y3 = tile[j0+r0+3][lane];
    for (int kk = 0; kk < r0; ++kk){
      float xk = tile[j0+kk][lane];
      y0 += dblk[r0+0][kk]*xk;
      y1 += dblk[r0+1][kk]*xk;
      y2 += dblk[r0+2][kk]*xk;
      y3 += dblk[r0+3][kk]*xk;
    }
    {
      float x0 = tile[j0+r0][lane], x1 = tile[j0+r0+1][lane], x2 = tile[j0+r0+2][lane];
      y1 += dblk[r0+1][r0]*x0;
      y2 += dblk[r0+2][r0]*x0 + dblk[r0+2][r0+1]*x1;
      y3 += dblk[r0+3][r0]*x0 + dblk[r0+3][r0+1]*x1 + dblk[r0+3][r0+2]*x2;
    }
    __syncthreads();
    tile[j0+r0+0][lane]=y0; tile[j0+r0+1][lane]=y1;
    tile[j0+r0+2][lane]=y2; tile[j0+r0+3][lane]=y3;
    __syncthreads();
    if (j0 + PW < NN){
      float x[PW];
      #pragma unroll
      for (int kk = 0; kk < PW; ++kk) x[kk] = tile[j0+kk][lane];
      const int nbelow = NN - j0 - PW;
      for (int i0 = wid*2; i0 < nbelow; i0 += 16){
        const int ia = j0 + PW + i0, ib = ia + 1;
        const float4* __restrict__ Ar0 = (const float4*)(A + (size_t)perm[ia]*NN + j0);
        const float4* __restrict__ Ar1 = (const float4*)(A + (size_t)perm[ib]*NN + j0);
        // hoist ALL 16 loads (in flight together), then FMA
        float4 A0=Ar0[0],A1=Ar0[1],A2=Ar0[2],A3=Ar0[3],A4=Ar0[4],A5=Ar0[5],A6=Ar0[6],A7=Ar0[7];
        float4 B0=Ar1[0],B1=Ar1[1],B2=Ar1[2],B3=Ar1[3],B4=Ar1[4],B5=Ar1[5],B6=Ar1[6],B7=Ar1[7];
        float acc0 = tile[ia][lane];
        float acc1 = tile[ib][lane];
        acc0 -= A0.x*x[0]  + A0.y*x[1]  + A0.z*x[2]  + A0.w*x[3];
        acc0 -= A1.x*x[4]  + A1.y*x[5]  + A1.z*x[6]  + A1.w*x[7];
        acc0 -= A2.x*x[8]  + A2.y*x[9]  + A2.z*x[10] + A2.w*x[11];
        acc0 -= A3.x*x[12] + A3.y*x[13] + A3.z*x[14] + A3.w*x[15];
        acc0 -= A4.x*x[16] + A4.y*x[17] + A4.z*x[18] + A4.w*x[19];
        acc0 -= A5.x*x[20] + A5.y*x[21] + A5.z*x[22] + A5.w*x[23];
        acc0 -= A6.x*x[24] + A6.y*x[25] + A6.z*x[26] + A6.w*x[27];
        acc0 -= A7.x*x[28] + A7.y*x[29] + A7.z*x[30] + A7.w*x[31];
        acc1 -= B0.x*x[0]  + B0.y*x[1]  + B0.z*x[2]  + B0.w*x[3];
        acc1 -= B1.x*x[4]  + B1.y*x[5]  + B1.z*x[6]  + B1.w*x[7];
        acc1 -= B2.x*x[8]  + B2.y*x[9]  + B2.z*x[10] + B2.w*x[11];
        acc1 -= B3.x*x[12] + B3.y*x[13] + B3.z*x[14] + B3.w*x[15];
        acc1 -= B4.x*x[16] + B4.y*x[17] + B4.z*x[18] + B4.w*x[19];
        acc1 -= B5.x*x[20] + B5.y*x[21] + B5.z*x[22] + B5.w*x[23];
        acc1 -= B6.x*x[24] + B6.y*x[25] + B6.z*x[26] + B6.w*x[27];
        acc1 -= B7.x*x[28] + B7.y*x[29] + B7.z*x[30] + B7.w*x[31];
        tile[ia][lane] = acc0;
        tile[ib][lane] = acc1;
      }
    }
    __syncthreads();
  }

  // ---- backward: d = Uinv-chain applied to y ----
  for (int J = NPAN-1; J >= 0; --J){
    const int j0 = J*PW;
    for (int e = t; e < PW*PW; e += 512){
      int r = e >> 5, c = e & 31;
      dblk[r][c] = A[(size_t)perm[j0+r]*NN + j0 + c];
    }
    __syncthreads();
    const int r0 = wid*4;
    float y0=0.f, y1=0.f, y2=0.f, y3=0.f;
    for (int kk = r0+4; kk < PW; ++kk){
      float xk = tile[j0+kk][lane];
      y0 += dblk[r0+0][kk]*xk;
      y1 += dblk[r0+1][kk]*xk;
      y2 += dblk[r0+2][kk]*xk;
      y3 += dblk[r0+3][kk]*xk;
    }
    {
      float x0 = tile[j0+r0][lane], x1 = tile[j0+r0+1][lane];
      float x2 = tile[j0+r0+2][lane], x3 = tile[j0+r0+3][lane];
      y0 += dblk[r0][r0]*x0 + dblk[r0][r0+1]*x1 + dblk[r0][r0+2]*x2 + dblk[r0][r0+3]*x3;
      y1 += dblk[r0+1][r0+1]*x1 + dblk[r0+1][r0+2]*x2 + dblk[r0+1][r0+3]*x3;
      y2 += dblk[r0+2][r0+2]*x2 + dblk[r0+2][r0+3]*x3;
      y3 += dblk[r0+3][r0+3]*x3;
    }
    __syncthreads();
    tile[j0+r0+0][lane]=y0; tile[j0+r0+1][lane]=y1;
    tile[j0+r0+2][lane]=y2; tile[j0+r0+3][lane]=y3;
    __syncthreads();
    if (j0 > 0){
      float x[PW];
      #pragma unroll
      for (int kk = 0; kk < PW; ++kk) x[kk] = tile[j0+kk][lane];
      for (int i0 = wid*2; i0 < j0; i0 += 16){
        const int ia = i0, ib = i0 + 1;
        const float4* __restrict__ Ar0 = (const float4*)(A + (size_t)perm[ia]*NN + j0);
        const float4* __restrict__ Ar1 = (const float4*)(A + (size_t)perm[ib]*NN + j0);
        float4 A0=Ar0[0],A1=Ar0[1],A2=Ar0[2],A3=Ar0[3],A4=Ar0[4],A5=Ar0[5],A6=Ar0[6],A7=Ar0[7];
        float4 B0=Ar1[0],B1=Ar1[1],B2=Ar1[2],B3=Ar1[3],B4=Ar1[4],B5=Ar1[5],B6=Ar1[6],B7=Ar1[7];
        float acc0 = tile[ia][lane];
        float acc1 = tile[ib][lane];
        acc0 -= A0.x*x[0]  + A0.y*x[1]  + A0.z*x[2]  + A0.w*x[3];
        acc0 -= A1.x*x[4]  + A1.y*x[5]  + A1.z*x[6]  + A1.w*x[7];
        acc0 -= A2.x*x[8]  + A2.y*x[9]  + A2.z*x[10] + A2.w*x[11];
        acc0 -= A3.x*x[12] + A3.y*x[13] + A3.z*x[14] + A3.w*x[15];
        acc0 -= A4.x*x[16] + A4.y*x[17] + A4.z*x[18] + A4.w*x[19];
        acc0 -= A5.x*x[20] + A5.y*x[21] + A5.z*x[22] + A5.w*x[23];
        acc0 -= A6.x*x[24] + A6.y*x[25] + A6.z*x[26] + A6.w*x[27];
        acc0 -= A7.x*x[28] + A7.y*x[29] + A7.z*x[30] + A7.w*x[31];
        acc1 -= B0.x*x[0]  + B0.y*x[1]  + B0.z*x[2]  + B0.w*x[3];
        acc1 -= B1.x*x[4]  + B1.y*x[5]  + B1.z*x[6]  + B1.w*x[7];
        acc1 -= B2.x*x[8]  + B2.y*x[9]  + B2.z*x[10] + B2.w*x[11];
        acc1 -= B3.x*x[12] + B3.y*x[13] + B3.z*x[14] + B3.w*x[15];
        acc1 -= B4.x*x[16] + B4.y*x[17] + B4.z*x[18] + B4.w*x[19];
        acc1 -= B5.x*x[20] + B5.y*x[21] + B5.z*x[22] + B5.w*x[23];
        acc1 -= B6.x*x[24] + B6.y*x[25] + B6.z*x[26] + B6.w*x[27];
        acc1 -= B7.x*x[28] + B7.y*x[29] + B7.z*x[30] + B7.w*x[31];
        tile[ia][lane] = acc0;
        tile[ib][lane] = acc1;
      }
    }
    __syncthreads();
  }

  // ---- epilogue: 8-wave partial column reductions + combine ----
  {
    const int p = c0 + lane;
    float sdv=0.f, sabs=0.f, s1v=0.f, s1=0.f;
    for (int j = wid*32; j < wid*32 + 32; ++j){
      float d = tile[j][lane];
      float v = val[(b*NN + j)*KK + k];
      if (v != v) v = 0.0f;
      float cb = C[((size_t)b*NN + j)*(NN+PP) + NN + p];
      float xb = sk*cb;
      float bo = (1.0f+xb)*expf(-xb);
      if (bad[b*NN + j]) bo = 0.0f;
      float d1 = bo / rs[j];
      sdv += d*v; sabs += fabsf(d); s1v += d1*v; s1 += d1;
    }
    ep[0][wid][lane]=sdv; ep[1][wid][lane]=sabs; ep[2][wid][lane]=s1v; ep[3][wid][lane]=s1;
  }
  __syncthreads();
  if (t < 64){
    float sdv=0.f, sabs=0.f, s1v=0.f, s1=0.f;
    #pragma unroll
    for (int w = 0; w < 8; ++w){
      sdv += ep[0][w][lane]; sabs += ep[1][w][lane];
      s1v += ep[2][w][lane]; s1  += ep[3][w][lane];
    }
    float wg    = fminf(fmaxf((sabs - 1.0f)*2.0f, 0.0f), 1.0f);
    float denom = fmaxf(s1, 1.0f);
    out[((size_t)b*PP + c0 + lane)*KK + k] = (1.0f - wg)*sdv + (wg/denom)*s1v;
  }
}

// ---------------------------------------------------------------------------
extern "C" void kernel_launch(void* const* d_in, const int* in_sizes, int n_in,
                              void* d_out, int out_size, void* d_ws, size_t ws_size,
                              hipStream_t stream)
{
  (void)in_sizes; (void)n_in; (void)out_size;
  const float* C    = (const float*)d_in[0];
  const float* val  = (const float*)d_in[1];
  const float* rm   = (const float*)d_in[2];
  const float* epsp = (const float*)d_in[3];
  const int*   bad  = (const int*)d_in[4];
  float* out = (float*)d_out;

  // per-system workspace: A (NN*NN f32) + rowsum (NN f32) + perm (NN i32)
  const size_t per_sys = (size_t)NN*NN*4 + (size_t)NN*4 + (size_t)NN*4;
  int chunk = (int)(ws_size / per_sys);
  if (chunk < 1)    chunk = 1;
  if (chunk > NSYS) chunk = NSYS;

  float* ws     = (float*)d_ws;
  float* A      = ws;
  float* rowsum = A + (size_t)chunk*NN*NN;
  int*   perm   = (int*)(rowsum + (size_t)chunk*NN);

  for (int s0 = 0; s0 < NSYS; s0 += chunk){
    int cs = (NSYS - s0 < chunk) ? (NSYS - s0) : chunk;
    build_kernel<<<cs*NN, 256, 0, stream>>>(C, rm, epsp, bad, A, rowsum, s0);
    lu_kernel<<<cs, 512, 0, stream>>>(A, perm);
    solve_epi_kernel<<<cs*4, 512, 0, stream>>>(A, perm, rowsum, C, val, bad, rm, out, s0);
  }
}